// Round 5
// baseline (628.181 us; speedup 1.0000x reference)
//
#include <hip/hip_runtime.h>

// approxmatch EMD (Fan et al.) on MI355X, B=4, N=M=4096, layout (B,3,N).
// Round 5: Morton-sort both point clouds (12-bit code, counting sort), tile
// bboxes at 128-point granularity, and wave-uniform bbox-mindist culling in
// every sweep kernel: exp2(ls2*d2) == 0.0f exactly when |ls2|*d2 > 150, so
// skipping tiles with mindist2 >= 160/|ls2| is bit-exact vs dense compute.
// Keeps round-4 structure: packed float2 lanes, exp-chaining (e_t = e_{t+1}^4),
// pass3(t)+pass1(t+1) fused, level-0 sweep specialcased. k_init folded into
// k_ratioL0, ratioR_l0 folded into k_cost_l0 staging.

#define NPTS 4096
#define BATCH 4
#define EMD_EPS 1e-9f
#define TILE 1024        // columns staged per LDS stage
#define RPW 4            // rows per wave, in registers
#define THREADS 256      // 4 waves
#define RPB 16           // rows per block = 4 waves * RPW
#define NBLK (NPTS / RPB)  // 256 row-blocks per batch
#define NTILE 32         // bbox tiles per batch side (128 points each)

__device__ __forceinline__ float fexp2(float x) {
#if __has_builtin(__builtin_amdgcn_exp2f)
    return __builtin_amdgcn_exp2f(x);
#else
    return exp2f(x);
#endif
}
__device__ __forceinline__ float fsqrt(float x) {
#if __has_builtin(__builtin_amdgcn_sqrtf)
    return __builtin_amdgcn_sqrtf(x);
#else
    return __sqrtf(x);
#endif
}

__device__ __forceinline__ float wave_reduce(float v) {
    v += __shfl_xor(v, 32);
    v += __shfl_xor(v, 16);
    v += __shfl_xor(v, 8);
    v += __shfl_xor(v, 4);
    v += __shfl_xor(v, 2);
    v += __shfl_xor(v, 1);
    return v;
}

// ---------------------------------------------------------------- morton sort
__device__ __forceinline__ unsigned spread4(unsigned v) {
    return (v & 1u) | ((v & 2u) << 2) | ((v & 4u) << 4) | ((v & 8u) << 6);
}

// counting sort by 12-bit morton code; one 1024-thread block per (side, batch)
__global__ __launch_bounds__(1024) void k_sort(
        const float* __restrict__ xyz1, const float* __restrict__ xyz2,
        float* __restrict__ x1s, float* __restrict__ x2s) {
    const int side = blockIdx.x, b = blockIdx.y;
    const float* src = (side ? xyz2 : xyz1) + b * 3 * NPTS;
    float* dst = (side ? x2s : x1s) + b * 3 * NPTS;
    const int tid = threadIdx.x;
    const int lane = tid & 63, wave = tid >> 6;

    __shared__ unsigned hist[4096];
    __shared__ unsigned short keys[4096];
    __shared__ unsigned warr[16];

    for (int i = tid; i < 4096; i += 1024) hist[i] = 0u;
    __syncthreads();
    for (int i = tid; i < NPTS; i += 1024) {
        float x = src[i], y = src[NPTS + i], z = src[2 * NPTS + i];
        unsigned qx = (unsigned)fminf(fmaxf((x + 5.0f) * 1.6f, 0.0f), 15.0f);
        unsigned qy = (unsigned)fminf(fmaxf((y + 5.0f) * 1.6f, 0.0f), 15.0f);
        unsigned qz = (unsigned)fminf(fmaxf((z + 5.0f) * 1.6f, 0.0f), 15.0f);
        unsigned key = spread4(qx) | (spread4(qy) << 1) | (spread4(qz) << 2);
        keys[i] = (unsigned short)key;
        atomicAdd(&hist[key], 1u);
    }
    __syncthreads();
    // exclusive scan of hist[4096]: 4 bins/thread, wave scan, cross-wave scan
    const int base = tid * 4;
    unsigned h0 = hist[base], h1 = hist[base + 1], h2 = hist[base + 2], h3 = hist[base + 3];
    unsigned st = h0 + h1 + h2 + h3;
    unsigned v = st;
    for (int d = 1; d < 64; d <<= 1) {
        unsigned u = __shfl_up(v, d);
        if (lane >= d) v += u;
    }
    if (lane == 63) warr[wave] = v;
    __syncthreads();
    if (tid == 0) {
        unsigned run = 0;
        for (int w = 0; w < 16; ++w) { unsigned t = warr[w]; warr[w] = run; run += t; }
    }
    __syncthreads();
    unsigned off = warr[wave] + (v - st);
    hist[base] = off;
    hist[base + 1] = off + h0;
    hist[base + 2] = off + h0 + h1;
    hist[base + 3] = off + h0 + h1 + h2;
    __syncthreads();
    // scatter
    for (int i = tid; i < NPTS; i += 1024) {
        unsigned k = keys[i];
        unsigned pos = atomicAdd(&hist[k], 1u);
        dst[pos] = src[i];
        dst[NPTS + pos] = src[NPTS + i];
        dst[2 * NPTS + pos] = src[2 * NPTS + i];
    }
}

// per-128-point-tile bboxes; grid (NTILE, BATCH, 2), 64 threads
__global__ void k_bbox(const float* __restrict__ x1s, const float* __restrict__ x2s,
                       float* __restrict__ bb1, float* __restrict__ bb2) {
    const int tile = blockIdx.x, b = blockIdx.y, side = blockIdx.z;
    const float* src = (side ? x2s : x1s) + b * 3 * NPTS + tile * 128;
    float* out = (side ? bb2 : bb1) + (b * NTILE + tile) * 8;
    const int lane = threadIdx.x;
    float mnx = 1e30f, mny = 1e30f, mnz = 1e30f;
    float mxx = -1e30f, mxy = -1e30f, mxz = -1e30f;
    for (int i = lane; i < 128; i += 64) {
        float x = src[i], y = src[NPTS + i], z = src[2 * NPTS + i];
        mnx = fminf(mnx, x); mny = fminf(mny, y); mnz = fminf(mnz, z);
        mxx = fmaxf(mxx, x); mxy = fmaxf(mxy, y); mxz = fmaxf(mxz, z);
    }
    for (int d = 32; d; d >>= 1) {
        mnx = fminf(mnx, __shfl_xor(mnx, d));
        mny = fminf(mny, __shfl_xor(mny, d));
        mnz = fminf(mnz, __shfl_xor(mnz, d));
        mxx = fmaxf(mxx, __shfl_xor(mxx, d));
        mxy = fmaxf(mxy, __shfl_xor(mxy, d));
        mxz = fmaxf(mxz, __shfl_xor(mxz, d));
    }
    if (lane == 0) {
        out[0] = mnx; out[1] = mny; out[2] = mnz;
        out[3] = mxx; out[4] = mxy; out[5] = mxz;
    }
}

// bbox-vs-wave-group mindist^2 (all operands wave-uniform)
#define BB_TEST(ti)                                                          \
    float bmnx = sBB[(ti) * 8 + 0], bmny = sBB[(ti) * 8 + 1],                \
          bmnz = sBB[(ti) * 8 + 2], bmxx = sBB[(ti) * 8 + 3],                \
          bmxy = sBB[(ti) * 8 + 4], bmxz = sBB[(ti) * 8 + 5];                \
    float ddx = fmaxf(0.0f, fmaxf(bmnx - gmxx, gmnx - bmxx));                \
    float ddy = fmaxf(0.0f, fmaxf(bmny - gmxy, gmny - bmxy));                \
    float ddz = fmaxf(0.0f, fmaxf(bmnz - gmxz, gmnz - bmxz));                \
    float md2 = fmaf(ddx, ddx, fmaf(ddy, ddy, ddz * ddz));

#define WAVE_BBOX()                                                          \
    float gmnx = fminf(fminf(px[0], px[1]), fminf(px[2], px[3]));            \
    float gmxx = fmaxf(fmaxf(px[0], px[1]), fmaxf(px[2], px[3]));            \
    float gmny = fminf(fminf(py[0], py[1]), fminf(py[2], py[3]));            \
    float gmxy = fmaxf(fmaxf(py[0], py[1]), fmaxf(py[2], py[3]));            \
    float gmnz = fminf(fminf(pz[0], pz[1]), fminf(pz[2], pz[3]));            \
    float gmxz = fmaxf(fmaxf(pz[0], pz[1]), fmaxf(pz[2], pz[3]));

// ---------------------------------------------------------------- pass 1 (sweep 0 only)
// remainR == 1, so ratioL_k = 1 / (EPS + sum_l exp2(ls2*d)); also inits
// remainL = remainR = 1 for its indices.
__global__ __launch_bounds__(THREADS, 2) void k_ratioL0(
        const float* __restrict__ x1s, const float* __restrict__ x2s,
        const float* __restrict__ bb2,
        float* __restrict__ ratioL, float* __restrict__ remainL,
        float* __restrict__ remainR, float ls2, float thresh) {
    const int b = blockIdx.y;
    const int tid = threadIdx.x;
    const int wave = tid >> 6;
    const int lane = tid & 63;
    const int row0 = blockIdx.x * RPB + wave * RPW;

    const float* x1 = x1s + b * 3 * NPTS;
    const float* x2 = x2s + b * 3 * NPTS;
    const float2* x2x = (const float2*)(x2);
    const float2* x2y = (const float2*)(x2 + NPTS);
    const float2* x2z = (const float2*)(x2 + 2 * NPTS);

    float px[RPW], py[RPW], pz[RPW];
    float2 acc[RPW];
#pragma unroll
    for (int r = 0; r < RPW; ++r) {
        px[r] = x1[row0 + r];
        py[r] = x1[NPTS + row0 + r];
        pz[r] = x1[2 * NPTS + row0 + r];
        acc[r] = make_float2(0.0f, 0.0f);
    }
    WAVE_BBOX();
    __shared__ float4 sA[TILE / 2];   // x0,x1,y0,y1
    __shared__ float2 sZ[TILE / 2];   // z0,z1
    __shared__ float sBB[NTILE * 8];
    if (tid < NTILE * 8) sBB[tid] = bb2[b * NTILE * 8 + tid];

    for (int c0 = 0; c0 < NPTS; c0 += TILE) {
        __syncthreads();
        for (int i = tid; i < TILE / 2; i += THREADS) {
            int e = c0 / 2 + i;
            float2 xx = x2x[e], yy = x2y[e];
            sA[i] = make_float4(xx.x, xx.y, yy.x, yy.y);
            sZ[i] = x2z[e];
        }
        __syncthreads();
#pragma unroll 2
        for (int j = 0; j < TILE / 128; ++j) {
            BB_TEST((c0 >> 7) + j);
            if (md2 < thresh) {
                float4 a = sA[lane + 64 * j];
                float2 z = sZ[lane + 64 * j];
#pragma unroll
                for (int r = 0; r < RPW; ++r) {
                    float dx0 = px[r] - a.x, dx1 = px[r] - a.y;
                    float dy0 = py[r] - a.z, dy1 = py[r] - a.w;
                    float dz0 = pz[r] - z.x, dz1 = pz[r] - z.y;
                    float d0 = fmaf(dx0, dx0, fmaf(dy0, dy0, dz0 * dz0));
                    float d1 = fmaf(dx1, dx1, fmaf(dy1, dy1, dz1 * dz1));
                    acc[r].x += fexp2(ls2 * d0);
                    acc[r].y += fexp2(ls2 * d1);
                }
            }
        }
    }
#pragma unroll
    for (int r = 0; r < RPW; ++r) {
        float s = wave_reduce(acc[r].x + acc[r].y);
        if (lane == 0) {
            int idx = b * NPTS + row0 + r;
            ratioL[idx] = 1.0f / (EMD_EPS + s);
            remainL[idx] = 1.0f;
            remainR[idx] = 1.0f;
        }
    }
}

// ---------------------------------------------------------------- pass 2
__global__ __launch_bounds__(THREADS, 2) void k_ratioR(
        const float* __restrict__ x1s, const float* __restrict__ x2s,
        const float* __restrict__ bb1,
        const float* __restrict__ ratioL, float* __restrict__ ratioR,
        float* __restrict__ remainR, float ls2, float thresh) {
    const int b = blockIdx.y;
    const int tid = threadIdx.x;
    const int wave = tid >> 6;
    const int lane = tid & 63;
    const int col0 = blockIdx.x * RPB + wave * RPW;

    const float* x1 = x1s + b * 3 * NPTS;
    const float* x2 = x2s + b * 3 * NPTS;
    const float2* x1x = (const float2*)(x1);
    const float2* x1y = (const float2*)(x1 + NPTS);
    const float2* x1z = (const float2*)(x1 + 2 * NPTS);
    const float2* wLv = (const float2*)(ratioL + b * NPTS);

    float px[RPW], py[RPW], pz[RPW];
    float2 acc[RPW];
#pragma unroll
    for (int r = 0; r < RPW; ++r) {
        px[r] = x2[col0 + r];
        py[r] = x2[NPTS + col0 + r];
        pz[r] = x2[2 * NPTS + col0 + r];
        acc[r] = make_float2(0.0f, 0.0f);
    }
    WAVE_BBOX();
    __shared__ float4 sA[TILE / 2];   // x0,x1,y0,y1
    __shared__ float4 sB[TILE / 2];   // z0,z1,w0,w1
    __shared__ float sBB[NTILE * 8];
    if (tid < NTILE * 8) sBB[tid] = bb1[b * NTILE * 8 + tid];

    for (int c0 = 0; c0 < NPTS; c0 += TILE) {
        __syncthreads();
        for (int i = tid; i < TILE / 2; i += THREADS) {
            int e = c0 / 2 + i;
            float2 xx = x1x[e], yy = x1y[e], zz = x1z[e], ww = wLv[e];
            sA[i] = make_float4(xx.x, xx.y, yy.x, yy.y);
            sB[i] = make_float4(zz.x, zz.y, ww.x, ww.y);
        }
        __syncthreads();
#pragma unroll 2
        for (int j = 0; j < TILE / 128; ++j) {
            BB_TEST((c0 >> 7) + j);
            if (md2 < thresh) {
                float4 a = sA[lane + 64 * j];
                float4 bq = sB[lane + 64 * j];
#pragma unroll
                for (int r = 0; r < RPW; ++r) {
                    float dx0 = px[r] - a.x, dx1 = px[r] - a.y;
                    float dy0 = py[r] - a.z, dy1 = py[r] - a.w;
                    float dz0 = pz[r] - bq.x, dz1 = pz[r] - bq.y;
                    float d0 = fmaf(dx0, dx0, fmaf(dy0, dy0, dz0 * dz0));
                    float d1 = fmaf(dx1, dx1, fmaf(dy1, dy1, dz1 * dz1));
                    acc[r].x = fmaf(fexp2(ls2 * d0), bq.z, acc[r].x);
                    acc[r].y = fmaf(fexp2(ls2 * d1), bq.w, acc[r].y);
                }
            }
        }
    }
#pragma unroll
    for (int r = 0; r < RPW; ++r) {
        float s = wave_reduce(acc[r].x + acc[r].y);
        if (lane == 0) {
            int idx = b * NPTS + col0 + r;
            float rv = remainR[idx];
            float sumr = rv * s;
            float cons = fminf(rv / (sumr + EMD_EPS), 1.0f);
            ratioR[idx] = cons * rv;
            remainR[idx] = fmaxf(0.0f, rv - sumr);
        }
    }
}

// ---------------------------------------------------------------- pass 3(t) + pass 1(t+1) fused
// SQ: e2 = exp2(ls2n*d); er = e2^4 * ratioR (ls2 == 4*ls2n exactly).
// !SQ (t=8): er = exp2(ls2*d)*ratioR, e2 == 1.
// Culling on thresh from ls2n: md2 >= 160/|ls2n| -> e2 == 0 -> er == 0 too.
template <bool SQ>
__global__ __launch_bounds__(THREADS, 2) void k_cost_fused(
        const float* __restrict__ x1s, const float* __restrict__ x2s,
        const float* __restrict__ bb2,
        float* __restrict__ ratioL, const float* __restrict__ ratioR,
        float* __restrict__ remainL, const float* __restrict__ remainR,
        float* __restrict__ cost_part, float ls2, float ls2n, float thresh,
        int initCost) {
    const int b = blockIdx.y;
    const int tid = threadIdx.x;
    const int wave = tid >> 6;
    const int lane = tid & 63;
    const int row0 = blockIdx.x * RPB + wave * RPW;

    const float* x1 = x1s + b * 3 * NPTS;
    const float* x2 = x2s + b * 3 * NPTS;
    const float2* x2x = (const float2*)(x2);
    const float2* x2y = (const float2*)(x2 + NPTS);
    const float2* x2z = (const float2*)(x2 + 2 * NPTS);
    const float2* wRv = (const float2*)(ratioR + b * NPTS);
    const float2* w2v = (const float2*)(remainR + b * NPTS);

    float px[RPW], py[RPW], pz[RPW];
    float2 acc_a[RPW], acc_c[RPW], acc_s[RPW];
#pragma unroll
    for (int r = 0; r < RPW; ++r) {
        px[r] = x1[row0 + r];
        py[r] = x1[NPTS + row0 + r];
        pz[r] = x1[2 * NPTS + row0 + r];
        acc_a[r] = make_float2(0.0f, 0.0f);
        acc_c[r] = make_float2(0.0f, 0.0f);
        acc_s[r] = make_float2(0.0f, 0.0f);
    }
    WAVE_BBOX();
    __shared__ float4 sA[TILE / 2];   // x0,x1,y0,y1
    __shared__ float4 sB[TILE / 2];   // z0,z1,wR0,wR1
    __shared__ float2 sC[TILE / 2];   // w20,w21
    __shared__ float sBB[NTILE * 8];
    __shared__ float s_cost[THREADS / 64];
    if (tid < NTILE * 8) sBB[tid] = bb2[b * NTILE * 8 + tid];

    for (int c0 = 0; c0 < NPTS; c0 += TILE) {
        __syncthreads();
        for (int i = tid; i < TILE / 2; i += THREADS) {
            int e = c0 / 2 + i;
            float2 xx = x2x[e], yy = x2y[e], zz = x2z[e], wr = wRv[e];
            sA[i] = make_float4(xx.x, xx.y, yy.x, yy.y);
            sB[i] = make_float4(zz.x, zz.y, wr.x, wr.y);
            sC[i] = w2v[e];
        }
        __syncthreads();
#pragma unroll 2
        for (int j = 0; j < TILE / 128; ++j) {
            BB_TEST((c0 >> 7) + j);
            if (md2 < thresh) {
                float4 a = sA[lane + 64 * j];
                float4 bq = sB[lane + 64 * j];
                float2 c = sC[lane + 64 * j];
#pragma unroll
                for (int r = 0; r < RPW; ++r) {
                    float dx0 = px[r] - a.x, dx1 = px[r] - a.y;
                    float dy0 = py[r] - a.z, dy1 = py[r] - a.w;
                    float dz0 = pz[r] - bq.x, dz1 = pz[r] - bq.y;
                    float d0 = fmaf(dx0, dx0, fmaf(dy0, dy0, dz0 * dz0));
                    float d1 = fmaf(dx1, dx1, fmaf(dy1, dy1, dz1 * dz1));
                    float er0, er1;
                    if (SQ) {
                        float e20 = fexp2(ls2n * d0);
                        float e21 = fexp2(ls2n * d1);
                        acc_s[r].x = fmaf(e20, c.x, acc_s[r].x);
                        acc_s[r].y = fmaf(e21, c.y, acc_s[r].y);
                        float e40 = e20 * e20, e41 = e21 * e21;
                        er0 = (e40 * e40) * bq.z;
                        er1 = (e41 * e41) * bq.w;
                    } else {
                        er0 = fexp2(ls2 * d0) * bq.z;
                        er1 = fexp2(ls2 * d1) * bq.w;
                        acc_s[r].x += c.x;
                        acc_s[r].y += c.y;
                    }
                    acc_a[r].x += er0;
                    acc_a[r].y += er1;
                    acc_c[r].x = fmaf(er0, fsqrt(d0), acc_c[r].x);
                    acc_c[r].y = fmaf(er1, fsqrt(d1), acc_c[r].y);
                }
            } else if (!SQ) {
                // unreachable (thresh == INF for !SQ), keeps acc_s exact
            }
        }
    }
    float wcost = 0.0f;
#pragma unroll
    for (int r = 0; r < RPW; ++r) {
        float sa = wave_reduce(acc_a[r].x + acc_a[r].y);
        float sc = wave_reduce(acc_c[r].x + acc_c[r].y);
        float ss = wave_reduce(acc_s[r].x + acc_s[r].y);
        if (lane == 0) {
            int idx = b * NPTS + row0 + r;
            float rl = ratioL[idx];
            float rem = fmaxf(0.0f, remainL[idx] - rl * sa);
            remainL[idx] = rem;
            ratioL[idx] = rem / (EMD_EPS + ss);   // next sweep's ratioL
            wcost = fmaf(rl, sc, wcost);
        }
    }
    if (lane == 0) s_cost[wave] = wcost;
    __syncthreads();
    if (tid == 0) {
        float t = s_cost[0] + s_cost[1] + s_cost[2] + s_cost[3];
        int ci = b * NBLK + blockIdx.x;
        cost_part[ci] = (initCost ? t : cost_part[ci] + t);
    }
}

// ---------------------------------------------------------------- level-0
__global__ void k_sum_ratioL(const float* __restrict__ ratioL, float* __restrict__ S_L) {
    const int b = blockIdx.x;
    const int tid = threadIdx.x;
    float s = 0.0f;
    for (int i = tid; i < NPTS; i += 256) s += ratioL[b * NPTS + i];
    s = wave_reduce(s);
    __shared__ float sw[4];
    if ((tid & 63) == 0) sw[tid >> 6] = s;
    __syncthreads();
    if (tid == 0) S_L[b] = sw[0] + sw[1] + sw[2] + sw[3];
}

// level-0 cost pass: e == 1. ratioR computed inline during staging from
// remainR and S_L (folds the old k_ratioR_l0 elementwise kernel).
__global__ __launch_bounds__(THREADS, 2) void k_cost_l0(
        const float* __restrict__ x1s, const float* __restrict__ x2s,
        const float* __restrict__ ratioL, const float* __restrict__ remainR,
        const float* __restrict__ S_L, float* __restrict__ cost_part) {
    const int b = blockIdx.y;
    const int tid = threadIdx.x;
    const int wave = tid >> 6;
    const int lane = tid & 63;
    const int row0 = blockIdx.x * RPB + wave * RPW;
    const float sL = S_L[b];

    const float* x1 = x1s + b * 3 * NPTS;
    const float* x2 = x2s + b * 3 * NPTS;
    const float2* x2x = (const float2*)(x2);
    const float2* x2y = (const float2*)(x2 + NPTS);
    const float2* x2z = (const float2*)(x2 + 2 * NPTS);
    const float2* wRv = (const float2*)(remainR + b * NPTS);

    float px[RPW], py[RPW], pz[RPW];
    float2 acc_c[RPW];
#pragma unroll
    for (int r = 0; r < RPW; ++r) {
        px[r] = x1[row0 + r];
        py[r] = x1[NPTS + row0 + r];
        pz[r] = x1[2 * NPTS + row0 + r];
        acc_c[r] = make_float2(0.0f, 0.0f);
    }
    __shared__ float4 sA[TILE / 2];
    __shared__ float4 sB[TILE / 2];
    __shared__ float s_cost[THREADS / 64];

    for (int c0 = 0; c0 < NPTS; c0 += TILE) {
        __syncthreads();
        for (int i = tid; i < TILE / 2; i += THREADS) {
            int e = c0 / 2 + i;
            float2 xx = x2x[e], yy = x2y[e], zz = x2z[e], rv = wRv[e];
            // ratioR_l0 inline: sumr = rv*S_L; wr = min(rv/(sumr+eps),1)*rv
            float wr0 = fminf(rv.x / (rv.x * sL + EMD_EPS), 1.0f) * rv.x;
            float wr1 = fminf(rv.y / (rv.y * sL + EMD_EPS), 1.0f) * rv.y;
            sA[i] = make_float4(xx.x, xx.y, yy.x, yy.y);
            sB[i] = make_float4(zz.x, zz.y, wr0, wr1);
        }
        __syncthreads();
#pragma unroll 2
        for (int j = 0; j < TILE / 128; ++j) {
            float4 a = sA[lane + 64 * j];
            float4 bq = sB[lane + 64 * j];
#pragma unroll
            for (int r = 0; r < RPW; ++r) {
                float dx0 = px[r] - a.x, dx1 = px[r] - a.y;
                float dy0 = py[r] - a.z, dy1 = py[r] - a.w;
                float dz0 = pz[r] - bq.x, dz1 = pz[r] - bq.y;
                float d0 = fmaf(dx0, dx0, fmaf(dy0, dy0, dz0 * dz0));
                float d1 = fmaf(dx1, dx1, fmaf(dy1, dy1, dz1 * dz1));
                acc_c[r].x = fmaf(bq.z, fsqrt(d0), acc_c[r].x);
                acc_c[r].y = fmaf(bq.w, fsqrt(d1), acc_c[r].y);
            }
        }
    }
    float wcost = 0.0f;
#pragma unroll
    for (int r = 0; r < RPW; ++r) {
        float sc = wave_reduce(acc_c[r].x + acc_c[r].y);
        if (lane == 0)
            wcost = fmaf(ratioL[b * NPTS + row0 + r], sc, wcost);
    }
    if (lane == 0) s_cost[wave] = wcost;
    __syncthreads();
    if (tid == 0) {
        float t = s_cost[0] + s_cost[1] + s_cost[2] + s_cost[3];
        cost_part[b * NBLK + blockIdx.x] += t;
    }
}

// ---------------------------------------------------------------- finalize
__global__ void k_final(const float* __restrict__ cost_part, float* __restrict__ out) {
    const int tid = threadIdx.x;
    float s = 0.0f;
    for (int i = tid; i < BATCH * NBLK; i += 256) s += cost_part[i];
    s = wave_reduce(s);
    __shared__ float sw[4];
    if ((tid & 63) == 0) sw[tid >> 6] = s;
    __syncthreads();
    if (tid == 0) out[0] = (sw[0] + sw[1] + sw[2] + sw[3]) / ((float)NPTS * (float)BATCH);
}

extern "C" void kernel_launch(void* const* d_in, const int* in_sizes, int n_in,
                              void* d_out, int out_size, void* d_ws, size_t ws_size,
                              hipStream_t stream) {
    const float* xyz1 = (const float*)d_in[0];
    const float* xyz2 = (const float*)d_in[1];
    float* out = (float*)d_out;

    const int BN = BATCH * NPTS;
    float* ws = (float*)d_ws;
    float* remainL  = ws;                      // BN
    float* remainR  = ws + 1 * BN;             // BN
    float* ratioL   = ws + 2 * BN;             // BN
    float* ratioR   = ws + 3 * BN;             // BN
    float* cost_part = ws + 4 * BN;            // BATCH*NBLK = 1024
    float* S_L      = cost_part + BATCH * NBLK;  // BATCH
    float* x1s      = S_L + 4;                 // 3*BN   (offset stays 8B-aligned)
    float* x2s      = x1s + 3 * BN;            // 3*BN
    float* bb1      = x2s + 3 * BN;            // BATCH*NTILE*8
    float* bb2      = bb1 + BATCH * NTILE * 8;

    // levels: -(4^j) for j = 7..-1, then 0; premultiplied by log2(e).
    // Consecutive levels differ by exactly 4x -> ls2[t] == 4*ls2[t+1] exactly.
    static const float levels[10] = {
        -16384.0f, -4096.0f, -1024.0f, -256.0f, -64.0f,
        -16.0f, -4.0f, -1.0f, -0.25f, 0.0f};
    float ls2[10], thr[10];
    for (int t = 0; t < 10; ++t) {
        ls2[t] = (float)(levels[t] * 1.4426950408889634);
        thr[t] = (t < 9) ? (160.0f / -ls2[t]) : 3.0e38f;
    }
    const float INF_THR = 3.0e38f;

    dim3 grid(NBLK, BATCH);

    k_sort<<<dim3(2, BATCH), 1024, 0, stream>>>(xyz1, xyz2, x1s, x2s);
    k_bbox<<<dim3(NTILE, BATCH, 2), 64, 0, stream>>>(x1s, x2s, bb1, bb2);

    k_ratioL0<<<grid, THREADS, 0, stream>>>(x1s, x2s, bb2, ratioL, remainL, remainR,
                                            ls2[0], thr[0]);
    for (int t = 0; t < 8; ++t) {
        k_ratioR<<<grid, THREADS, 0, stream>>>(x1s, x2s, bb1, ratioL, ratioR, remainR,
                                               ls2[t], thr[t]);
        k_cost_fused<true><<<grid, THREADS, 0, stream>>>(x1s, x2s, bb2, ratioL, ratioR,
                                                         remainL, remainR, cost_part,
                                                         ls2[t], ls2[t + 1], thr[t + 1],
                                                         t == 0 ? 1 : 0);
    }
    // t = 8: next level is 0 (no 4x relation) -> direct-exp variant, no culling
    k_ratioR<<<grid, THREADS, 0, stream>>>(x1s, x2s, bb1, ratioL, ratioR, remainR,
                                           ls2[8], thr[8]);
    k_cost_fused<false><<<grid, THREADS, 0, stream>>>(x1s, x2s, bb2, ratioL, ratioR,
                                                      remainL, remainR, cost_part,
                                                      ls2[8], 0.0f, INF_THR, 0);
    // sweep 9 (level == 0): suml handled by acc_s above; ratioR inline in cost_l0
    k_sum_ratioL<<<BATCH, 256, 0, stream>>>(ratioL, S_L);
    k_cost_l0<<<grid, THREADS, 0, stream>>>(x1s, x2s, ratioL, remainR, S_L, cost_part);
    k_final<<<1, 256, 0, stream>>>(cost_part, out);
}

// Round 6
// 532.601 us; speedup vs baseline: 1.1795x; 1.1795x over previous
//
#include <hip/hip_runtime.h>

// approxmatch EMD (Fan et al.) on MI355X, B=4, N=M=4096, layout (B,3,N).
// Round 6: dense-path throughput round (culling/sort machinery dropped —
// Morton-tile bbox culling measured as a wash in R5: octant-corner overlap).
// - RPW=2, RPB=8 -> grid 2048 blocks (8 blocks/CU possible vs 4 before)
// - ext_vector_type(2) math -> v_pk_fma_f32 / v_pk_mul_f32 formation
// - exp-chaining kept: e_t = (e_{t+1})^4 (levels are exact powers of 4)
// - pass3(t)+pass1(t+1) fused; level-0 sweep specialcased.

#define NPTS 4096
#define BATCH 4
#define EMD_EPS 1e-9f
#define TILE 1024        // columns staged per LDS stage
#define RPW 2            // rows per wave, in registers
#define THREADS 256      // 4 waves
#define RPB 8            // rows per block = 4 waves * RPW
#define NBLK (NPTS / RPB)  // 512 row-blocks per batch

typedef float v2f __attribute__((ext_vector_type(2)));

__device__ __forceinline__ float fexp2(float x) {
#if __has_builtin(__builtin_amdgcn_exp2f)
    return __builtin_amdgcn_exp2f(x);
#else
    return exp2f(x);
#endif
}
__device__ __forceinline__ float fsqrt(float x) {
#if __has_builtin(__builtin_amdgcn_sqrtf)
    return __builtin_amdgcn_sqrtf(x);
#else
    return __sqrtf(x);
#endif
}

__device__ __forceinline__ float wave_reduce(float v) {
    v += __shfl_xor(v, 32);
    v += __shfl_xor(v, 16);
    v += __shfl_xor(v, 8);
    v += __shfl_xor(v, 4);
    v += __shfl_xor(v, 2);
    v += __shfl_xor(v, 1);
    return v;
}

// ---------------------------------------------------------------- pass 1 (sweep 0 only)
// remainR == 1, so ratioL_k = 1 / (EPS + sum_l exp2(ls2*d)); also inits
// remainL = remainR = 1 and cost_part = 0 for its indices.
__global__ __launch_bounds__(THREADS, 6) void k_ratioL0(
        const float* __restrict__ xyz1, const float* __restrict__ xyz2,
        float* __restrict__ ratioL, float* __restrict__ remainL,
        float* __restrict__ remainR, float ls2) {
    const int b = blockIdx.y;
    const int tid = threadIdx.x;
    const int wave = tid >> 6;
    const int lane = tid & 63;
    const int row0 = blockIdx.x * RPB + wave * RPW;

    const float* x1 = xyz1 + b * 3 * NPTS;
    const float* x2 = xyz2 + b * 3 * NPTS;
    const float2* x2x = (const float2*)(x2);
    const float2* x2y = (const float2*)(x2 + NPTS);
    const float2* x2z = (const float2*)(x2 + 2 * NPTS);

    float px[RPW], py[RPW], pz[RPW];
    v2f acc[RPW];
#pragma unroll
    for (int r = 0; r < RPW; ++r) {
        px[r] = x1[row0 + r];
        py[r] = x1[NPTS + row0 + r];
        pz[r] = x1[2 * NPTS + row0 + r];
        acc[r] = (v2f)(0.0f);
    }
    __shared__ float4 sA[TILE / 2];   // x0,x1,y0,y1
    __shared__ float2 sZ[TILE / 2];   // z0,z1

    for (int c0 = 0; c0 < NPTS; c0 += TILE) {
        __syncthreads();
        for (int i = tid; i < TILE / 2; i += THREADS) {
            int e = c0 / 2 + i;
            float2 xx = x2x[e], yy = x2y[e];
            sA[i] = make_float4(xx.x, xx.y, yy.x, yy.y);
            sZ[i] = x2z[e];
        }
        __syncthreads();
#pragma unroll 2
        for (int j = 0; j < TILE / 128; ++j) {
            float4 a = sA[lane + 64 * j];
            float2 z = sZ[lane + 64 * j];
            v2f ax = {a.x, a.y}, ay = {a.z, a.w}, az = {z.x, z.y};
#pragma unroll
            for (int r = 0; r < RPW; ++r) {
                v2f dx = px[r] - ax, dy = py[r] - ay, dz = pz[r] - az;
                v2f d = dx * dx + dy * dy + dz * dz;
                v2f sd = ls2 * d;
                v2f e2 = {fexp2(sd.x), fexp2(sd.y)};
                acc[r] += e2;
            }
        }
    }
#pragma unroll
    for (int r = 0; r < RPW; ++r) {
        float s = wave_reduce(acc[r].x + acc[r].y);
        if (lane == 0) {
            int idx = b * NPTS + row0 + r;
            ratioL[idx] = 1.0f / (EMD_EPS + s);
            remainL[idx] = 1.0f;
            remainR[idx] = 1.0f;
        }
    }
}

// ---------------------------------------------------------------- pass 2
// per column l: s = sum_k e*ratioL_k ; sumr = remainR*s ;
// ratioR = min(remainR/(sumr+EPS),1)*remainR ; remainR = max(0, remainR-sumr)
__global__ __launch_bounds__(THREADS, 6) void k_ratioR(
        const float* __restrict__ xyz1, const float* __restrict__ xyz2,
        const float* __restrict__ ratioL, float* __restrict__ ratioR,
        float* __restrict__ remainR, float ls2) {
    const int b = blockIdx.y;
    const int tid = threadIdx.x;
    const int wave = tid >> 6;
    const int lane = tid & 63;
    const int col0 = blockIdx.x * RPB + wave * RPW;

    const float* x1 = xyz1 + b * 3 * NPTS;
    const float* x2 = xyz2 + b * 3 * NPTS;
    const float2* x1x = (const float2*)(x1);
    const float2* x1y = (const float2*)(x1 + NPTS);
    const float2* x1z = (const float2*)(x1 + 2 * NPTS);
    const float2* wLv = (const float2*)(ratioL + b * NPTS);

    float px[RPW], py[RPW], pz[RPW];
    v2f acc[RPW];
#pragma unroll
    for (int r = 0; r < RPW; ++r) {
        px[r] = x2[col0 + r];
        py[r] = x2[NPTS + col0 + r];
        pz[r] = x2[2 * NPTS + col0 + r];
        acc[r] = (v2f)(0.0f);
    }
    __shared__ float4 sA[TILE / 2];   // x0,x1,y0,y1
    __shared__ float4 sB[TILE / 2];   // z0,z1,w0,w1

    for (int c0 = 0; c0 < NPTS; c0 += TILE) {
        __syncthreads();
        for (int i = tid; i < TILE / 2; i += THREADS) {
            int e = c0 / 2 + i;
            float2 xx = x1x[e], yy = x1y[e], zz = x1z[e], ww = wLv[e];
            sA[i] = make_float4(xx.x, xx.y, yy.x, yy.y);
            sB[i] = make_float4(zz.x, zz.y, ww.x, ww.y);
        }
        __syncthreads();
#pragma unroll 2
        for (int j = 0; j < TILE / 128; ++j) {
            float4 a = sA[lane + 64 * j];
            float4 bq = sB[lane + 64 * j];
            v2f ax = {a.x, a.y}, ay = {a.z, a.w};
            v2f az = {bq.x, bq.y}, aw = {bq.z, bq.w};
#pragma unroll
            for (int r = 0; r < RPW; ++r) {
                v2f dx = px[r] - ax, dy = py[r] - ay, dz = pz[r] - az;
                v2f d = dx * dx + dy * dy + dz * dz;
                v2f sd = ls2 * d;
                v2f e2 = {fexp2(sd.x), fexp2(sd.y)};
                acc[r] += e2 * aw;
            }
        }
    }
#pragma unroll
    for (int r = 0; r < RPW; ++r) {
        float s = wave_reduce(acc[r].x + acc[r].y);
        if (lane == 0) {
            int idx = b * NPTS + col0 + r;
            float rv = remainR[idx];
            float sumr = rv * s;
            float cons = fminf(rv / (sumr + EMD_EPS), 1.0f);
            ratioR[idx] = cons * rv;
            remainR[idx] = fmaxf(0.0f, rv - sumr);
        }
    }
}

// ---------------------------------------------------------------- pass 3(t) + pass 1(t+1) fused
// SQ: e2 = exp2(ls2n*d); er = e2^4 * ratioR (ls2 == 4*ls2n exactly).
// !SQ (t=8): er = exp2(ls2*d)*ratioR, e2 == 1 (ls2n == 0).
// acc_a = sum er ; acc_c = sum er*sqrt(d) ; acc_s = sum e2*remainR
template <bool SQ>
__global__ __launch_bounds__(THREADS, 6) void k_cost_fused(
        const float* __restrict__ xyz1, const float* __restrict__ xyz2,
        float* __restrict__ ratioL, const float* __restrict__ ratioR,
        float* __restrict__ remainL, const float* __restrict__ remainR,
        float* __restrict__ cost_part, float ls2, float ls2n, int initCost) {
    const int b = blockIdx.y;
    const int tid = threadIdx.x;
    const int wave = tid >> 6;
    const int lane = tid & 63;
    const int row0 = blockIdx.x * RPB + wave * RPW;

    const float* x1 = xyz1 + b * 3 * NPTS;
    const float* x2 = xyz2 + b * 3 * NPTS;
    const float2* x2x = (const float2*)(x2);
    const float2* x2y = (const float2*)(x2 + NPTS);
    const float2* x2z = (const float2*)(x2 + 2 * NPTS);
    const float2* wRv = (const float2*)(ratioR + b * NPTS);
    const float2* w2v = (const float2*)(remainR + b * NPTS);

    float px[RPW], py[RPW], pz[RPW];
    v2f acc_a[RPW], acc_c[RPW], acc_s[RPW];
#pragma unroll
    for (int r = 0; r < RPW; ++r) {
        px[r] = x1[row0 + r];
        py[r] = x1[NPTS + row0 + r];
        pz[r] = x1[2 * NPTS + row0 + r];
        acc_a[r] = (v2f)(0.0f);
        acc_c[r] = (v2f)(0.0f);
        acc_s[r] = (v2f)(0.0f);
    }
    __shared__ float4 sA[TILE / 2];   // x0,x1,y0,y1
    __shared__ float4 sB[TILE / 2];   // z0,z1,wR0,wR1
    __shared__ float2 sC[TILE / 2];   // w20,w21
    __shared__ float s_cost[THREADS / 64];

    for (int c0 = 0; c0 < NPTS; c0 += TILE) {
        __syncthreads();
        for (int i = tid; i < TILE / 2; i += THREADS) {
            int e = c0 / 2 + i;
            float2 xx = x2x[e], yy = x2y[e], zz = x2z[e], wr = wRv[e];
            sA[i] = make_float4(xx.x, xx.y, yy.x, yy.y);
            sB[i] = make_float4(zz.x, zz.y, wr.x, wr.y);
            sC[i] = w2v[e];
        }
        __syncthreads();
#pragma unroll 2
        for (int j = 0; j < TILE / 128; ++j) {
            float4 a = sA[lane + 64 * j];
            float4 bq = sB[lane + 64 * j];
            float2 c = sC[lane + 64 * j];
            v2f ax = {a.x, a.y}, ay = {a.z, a.w};
            v2f az = {bq.x, bq.y}, wr = {bq.z, bq.w};
            v2f cw = {c.x, c.y};
#pragma unroll
            for (int r = 0; r < RPW; ++r) {
                v2f dx = px[r] - ax, dy = py[r] - ay, dz = pz[r] - az;
                v2f d = dx * dx + dy * dy + dz * dz;
                v2f er;
                if (SQ) {
                    v2f sd = ls2n * d;
                    v2f e2 = {fexp2(sd.x), fexp2(sd.y)};
                    acc_s[r] += e2 * cw;
                    v2f e4 = e2 * e2;
                    er = (e4 * e4) * wr;
                } else {
                    v2f sd = ls2 * d;
                    v2f e1 = {fexp2(sd.x), fexp2(sd.y)};
                    er = e1 * wr;
                    acc_s[r] += cw;   // e2 == 1 when ls2n == 0
                }
                acc_a[r] += er;
                v2f sq = {fsqrt(d.x), fsqrt(d.y)};
                acc_c[r] += er * sq;
            }
        }
    }
    float wcost = 0.0f;
#pragma unroll
    for (int r = 0; r < RPW; ++r) {
        float sa = wave_reduce(acc_a[r].x + acc_a[r].y);
        float sc = wave_reduce(acc_c[r].x + acc_c[r].y);
        float ss = wave_reduce(acc_s[r].x + acc_s[r].y);
        if (lane == 0) {
            int idx = b * NPTS + row0 + r;
            float rl = ratioL[idx];
            float rem = fmaxf(0.0f, remainL[idx] - rl * sa);
            remainL[idx] = rem;
            ratioL[idx] = rem / (EMD_EPS + ss);   // next sweep's ratioL
            wcost = fmaf(rl, sc, wcost);
        }
    }
    if (lane == 0) s_cost[wave] = wcost;
    __syncthreads();
    if (tid == 0) {
        float t = s_cost[0] + s_cost[1] + s_cost[2] + s_cost[3];
        int ci = b * NBLK + blockIdx.x;
        cost_part[ci] = (initCost ? t : cost_part[ci] + t);
    }
}

// ---------------------------------------------------------------- level-0
__global__ void k_sum_ratioL(const float* __restrict__ ratioL, float* __restrict__ S_L) {
    const int b = blockIdx.x;
    const int tid = threadIdx.x;
    float s = 0.0f;
    for (int i = tid; i < NPTS; i += 256) s += ratioL[b * NPTS + i];
    s = wave_reduce(s);
    __shared__ float sw[4];
    if ((tid & 63) == 0) sw[tid >> 6] = s;
    __syncthreads();
    if (tid == 0) S_L[b] = sw[0] + sw[1] + sw[2] + sw[3];
}

// level-0 cost pass: e == 1. ratioR computed inline during staging from
// remainR and S_L.
__global__ __launch_bounds__(THREADS, 6) void k_cost_l0(
        const float* __restrict__ xyz1, const float* __restrict__ xyz2,
        const float* __restrict__ ratioL, const float* __restrict__ remainR,
        const float* __restrict__ S_L, float* __restrict__ cost_part) {
    const int b = blockIdx.y;
    const int tid = threadIdx.x;
    const int wave = tid >> 6;
    const int lane = tid & 63;
    const int row0 = blockIdx.x * RPB + wave * RPW;
    const float sL = S_L[b];

    const float* x1 = xyz1 + b * 3 * NPTS;
    const float* x2 = xyz2 + b * 3 * NPTS;
    const float2* x2x = (const float2*)(x2);
    const float2* x2y = (const float2*)(x2 + NPTS);
    const float2* x2z = (const float2*)(x2 + 2 * NPTS);
    const float2* wRv = (const float2*)(remainR + b * NPTS);

    float px[RPW], py[RPW], pz[RPW];
    v2f acc_c[RPW];
#pragma unroll
    for (int r = 0; r < RPW; ++r) {
        px[r] = x1[row0 + r];
        py[r] = x1[NPTS + row0 + r];
        pz[r] = x1[2 * NPTS + row0 + r];
        acc_c[r] = (v2f)(0.0f);
    }
    __shared__ float4 sA[TILE / 2];
    __shared__ float4 sB[TILE / 2];
    __shared__ float s_cost[THREADS / 64];

    for (int c0 = 0; c0 < NPTS; c0 += TILE) {
        __syncthreads();
        for (int i = tid; i < TILE / 2; i += THREADS) {
            int e = c0 / 2 + i;
            float2 xx = x2x[e], yy = x2y[e], zz = x2z[e], rv = wRv[e];
            // ratioR_l0 inline: sumr = rv*S_L; wr = min(rv/(sumr+eps),1)*rv
            float wr0 = fminf(rv.x / (rv.x * sL + EMD_EPS), 1.0f) * rv.x;
            float wr1 = fminf(rv.y / (rv.y * sL + EMD_EPS), 1.0f) * rv.y;
            sA[i] = make_float4(xx.x, xx.y, yy.x, yy.y);
            sB[i] = make_float4(zz.x, zz.y, wr0, wr1);
        }
        __syncthreads();
#pragma unroll 2
        for (int j = 0; j < TILE / 128; ++j) {
            float4 a = sA[lane + 64 * j];
            float4 bq = sB[lane + 64 * j];
            v2f ax = {a.x, a.y}, ay = {a.z, a.w};
            v2f az = {bq.x, bq.y}, wr = {bq.z, bq.w};
#pragma unroll
            for (int r = 0; r < RPW; ++r) {
                v2f dx = px[r] - ax, dy = py[r] - ay, dz = pz[r] - az;
                v2f d = dx * dx + dy * dy + dz * dz;
                v2f sq = {fsqrt(d.x), fsqrt(d.y)};
                acc_c[r] += wr * sq;
            }
        }
    }
    float wcost = 0.0f;
#pragma unroll
    for (int r = 0; r < RPW; ++r) {
        float sc = wave_reduce(acc_c[r].x + acc_c[r].y);
        if (lane == 0)
            wcost = fmaf(ratioL[b * NPTS + row0 + r], sc, wcost);
    }
    if (lane == 0) s_cost[wave] = wcost;
    __syncthreads();
    if (tid == 0) {
        float t = s_cost[0] + s_cost[1] + s_cost[2] + s_cost[3];
        cost_part[b * NBLK + blockIdx.x] += t;
    }
}

// ---------------------------------------------------------------- finalize
__global__ void k_final(const float* __restrict__ cost_part, float* __restrict__ out) {
    const int tid = threadIdx.x;
    float s = 0.0f;
    for (int i = tid; i < BATCH * NBLK; i += 256) s += cost_part[i];
    s = wave_reduce(s);
    __shared__ float sw[4];
    if ((tid & 63) == 0) sw[tid >> 6] = s;
    __syncthreads();
    if (tid == 0) out[0] = (sw[0] + sw[1] + sw[2] + sw[3]) / ((float)NPTS * (float)BATCH);
}

extern "C" void kernel_launch(void* const* d_in, const int* in_sizes, int n_in,
                              void* d_out, int out_size, void* d_ws, size_t ws_size,
                              hipStream_t stream) {
    const float* xyz1 = (const float*)d_in[0];
    const float* xyz2 = (const float*)d_in[1];
    float* out = (float*)d_out;

    const int BN = BATCH * NPTS;
    float* ws = (float*)d_ws;
    float* remainL  = ws;                      // BN
    float* remainR  = ws + 1 * BN;             // BN
    float* ratioL   = ws + 2 * BN;             // BN
    float* ratioR   = ws + 3 * BN;             // BN
    float* cost_part = ws + 4 * BN;            // BATCH*NBLK = 2048
    float* S_L      = cost_part + BATCH * NBLK;  // BATCH

    // levels: -(4^j) for j = 7..-1, then 0; premultiplied by log2(e).
    // Consecutive levels differ by exactly 4x -> ls2[t] == 4*ls2[t+1] exactly.
    static const float levels[10] = {
        -16384.0f, -4096.0f, -1024.0f, -256.0f, -64.0f,
        -16.0f, -4.0f, -1.0f, -0.25f, 0.0f};
    float ls2[10];
    for (int t = 0; t < 10; ++t)
        ls2[t] = (float)(levels[t] * 1.4426950408889634);

    dim3 grid(NBLK, BATCH);

    k_ratioL0<<<grid, THREADS, 0, stream>>>(xyz1, xyz2, ratioL, remainL, remainR, ls2[0]);
    for (int t = 0; t < 8; ++t) {
        k_ratioR<<<grid, THREADS, 0, stream>>>(xyz1, xyz2, ratioL, ratioR, remainR, ls2[t]);
        k_cost_fused<true><<<grid, THREADS, 0, stream>>>(xyz1, xyz2, ratioL, ratioR,
                                                         remainL, remainR, cost_part,
                                                         ls2[t], ls2[t + 1], t == 0 ? 1 : 0);
    }
    // t = 8: next level is 0 (no 4x relation) -> direct-exp variant
    k_ratioR<<<grid, THREADS, 0, stream>>>(xyz1, xyz2, ratioL, ratioR, remainR, ls2[8]);
    k_cost_fused<false><<<grid, THREADS, 0, stream>>>(xyz1, xyz2, ratioL, ratioR,
                                                      remainL, remainR, cost_part,
                                                      ls2[8], 0.0f, 0);
    // sweep 9 (level == 0): suml handled by acc_s above; ratioR inline in cost_l0
    k_sum_ratioL<<<BATCH, 256, 0, stream>>>(ratioL, S_L);
    k_cost_l0<<<grid, THREADS, 0, stream>>>(xyz1, xyz2, ratioL, remainR, S_L, cost_part);
    k_final<<<1, 256, 0, stream>>>(cost_part, out);
}